// Round 1
// baseline (1144.258 us; speedup 1.0000x reference)
//
#include <hip/hip_runtime.h>
#include <hip/hip_bf16.h>
#include <cstdint>
#include <cstddef>

typedef __attribute__((ext_vector_type(4))) float f32x4;
typedef __attribute__((ext_vector_type(8))) short s16x8;

#define D_ 128
#define H_ 512
#define CAT_ 384
#define BM 64
#define PC 392          // cat LDS pitch (elements): 384 + 8 pad -> 2-way bank alias (free)
#define PH 520          // h LDS pitch: 512 + 8 pad
#define PY 132          // y (f32) LDS pitch
#define BUF_BYTES 66560 // 64*520*2
#define LDS_BYTES (2 * BUF_BYTES)

__device__ __forceinline__ unsigned short f2bf(float x) {
  union { float f; unsigned u; } t; t.f = x;
  unsigned r = t.u + 0x7FFFu + ((t.u >> 16) & 1u); // round-to-nearest-even
  return (unsigned short)(r >> 16);
}

// One K-panel GEMM: A [64 x KDIM] bf16 in LDS (row-major, pitch apitch),
// B = Wt [N x KDIM] bf16 in global (pre-transposed, K contiguous).
// Wave computes 64 x (NFRAG*16) output via mfma_f32_16x16x32_bf16.
template<int KDIM, int NFRAG>
__device__ __forceinline__ void gemm_tile(const unsigned short* A, int apitch,
                                          const unsigned short* __restrict__ Wt,
                                          int wcol0, int lane,
                                          f32x4 (&acc)[4][NFRAG]) {
  const int arow = lane & 15;
  const int ak = (lane >> 4) * 8;
  #pragma unroll 2
  for (int kk = 0; kk < KDIM / 32; ++kk) {
    const int kof = kk * 32 + ak;
    s16x8 a[4], b[NFRAG];
    #pragma unroll
    for (int m = 0; m < 4; ++m)
      a[m] = *(const s16x8*)(A + (m * 16 + arow) * apitch + kof);
    #pragma unroll
    for (int n = 0; n < NFRAG; ++n)
      b[n] = *(const s16x8*)(Wt + (wcol0 + n * 16 + arow) * KDIM + kof);
    #pragma unroll
    for (int m = 0; m < 4; ++m)
      #pragma unroll
      for (int n = 0; n < NFRAG; ++n)
        acc[m][n] = __builtin_amdgcn_mfma_f32_16x16x32_bf16(a[m], b[n], acc[m][n], 0, 0, 0);
  }
}

// bias + SiLU + bf16 -> LDS h buffer (C/D layout: col = lane&15, row = (lane>>4)*4 + r)
template<int NFRAG>
__device__ __forceinline__ void silu_store(const f32x4 (&acc)[4][NFRAG],
                                           const float* __restrict__ bias,
                                           int wcol0, int c0, int r0,
                                           unsigned short* Hout) {
  #pragma unroll
  for (int n = 0; n < NFRAG; ++n) {
    const int col = wcol0 + n * 16 + c0;
    const float bb = bias[col];
    #pragma unroll
    for (int m = 0; m < 4; ++m) {
      #pragma unroll
      for (int r = 0; r < 4; ++r) {
        const float x = acc[m][n][r] + bb;
        const float sg = 1.0f / (1.0f + __expf(-x));
        Hout[(m * 16 + r0 + r) * PH + col] = f2bf(x * sg);
      }
    }
  }
}

__global__ __launch_bounds__(512, 2)
void edge_mlp_fused(const float* __restrict__ efeat,
                    const float* __restrict__ src_feat,
                    const float* __restrict__ dst_feat,
                    const int* __restrict__ src_idx,
                    const int* __restrict__ dst_idx,
                    const unsigned short* __restrict__ W1T,
                    const unsigned short* __restrict__ W2T,
                    const unsigned short* __restrict__ W3T,
                    const float* __restrict__ b1,
                    const float* __restrict__ b2,
                    const float* __restrict__ b3,
                    const float* __restrict__ gamma,
                    const float* __restrict__ beta,
                    float* __restrict__ out) {
  extern __shared__ char smem[];
  unsigned short* bufU = (unsigned short*)smem;               // cat (pitch 392) -> h2 (pitch 520)
  unsigned short* bufB = (unsigned short*)(smem + BUF_BYTES); // h1 (pitch 520) -> y f32
  float* yb = (float*)(smem + BUF_BYTES);

  const int tid = threadIdx.x;
  const int lane = tid & 63;
  const int wave = tid >> 6;
  const int e0 = blockIdx.x * BM;

  // ---- phase 0: gather + concat -> bf16 LDS (coalesced float4 reads) ----
  {
    const int row = tid >> 3, j = tid & 7;
    const int e = e0 + row;
    const float* p0 = efeat + (size_t)e * D_;
    const float* p1 = src_feat + (size_t)src_idx[e] * D_;
    const float* p2 = dst_feat + (size_t)dst_idx[e] * D_;
    const float* bases[3] = {p0, p1, p2};
    unsigned short* crow = bufU + row * PC;
    #pragma unroll
    for (int s = 0; s < 3; ++s) {
      #pragma unroll
      for (int q = 0; q < 4; ++q) {
        const int c4 = 4 * j + 32 * q;
        const float4 v = *(const float4*)(bases[s] + c4);
        ushort4 w;
        w.x = f2bf(v.x); w.y = f2bf(v.y); w.z = f2bf(v.z); w.w = f2bf(v.w);
        *(ushort4*)(crow + s * D_ + c4) = w;
      }
    }
  }
  __syncthreads();

  const int c0 = lane & 15, r0 = (lane >> 4) * 4;

  // ---- GEMM1: [64,384] @ W1 -> silu -> h1 (bufB) ----
  {
    f32x4 acc[4][4];
    #pragma unroll
    for (int m = 0; m < 4; ++m)
      #pragma unroll
      for (int n = 0; n < 4; ++n)
        acc[m][n] = (f32x4){0.f, 0.f, 0.f, 0.f};
    gemm_tile<CAT_, 4>(bufU, PC, W1T, wave * 64, lane, acc);
    silu_store<4>(acc, b1, wave * 64, c0, r0, bufB);
  }
  __syncthreads();

  // ---- GEMM2: [64,512] @ W2 -> silu -> h2 (bufU) ----
  {
    f32x4 acc[4][4];
    #pragma unroll
    for (int m = 0; m < 4; ++m)
      #pragma unroll
      for (int n = 0; n < 4; ++n)
        acc[m][n] = (f32x4){0.f, 0.f, 0.f, 0.f};
    gemm_tile<H_, 4>(bufB, PH, W2T, wave * 64, lane, acc);
    silu_store<4>(acc, b2, wave * 64, c0, r0, bufU);
  }
  __syncthreads();

  // ---- GEMM3: [64,512] @ W3 + b3 -> y (f32, bufB) ----
  {
    f32x4 acc[4][1];
    #pragma unroll
    for (int m = 0; m < 4; ++m)
      acc[m][0] = (f32x4){0.f, 0.f, 0.f, 0.f};
    gemm_tile<H_, 1>(bufU, PH, W3T, wave * 16, lane, acc);
    const int col = wave * 16 + c0;
    const float bb = b3[col];
    #pragma unroll
    for (int m = 0; m < 4; ++m)
      #pragma unroll
      for (int r = 0; r < 4; ++r)
        yb[(m * 16 + r0 + r) * PY + col] = acc[m][0][r] + bb;
  }
  __syncthreads();

  // ---- LayerNorm (f32) + store: 8 threads per row ----
  {
    const int row = tid >> 3, j = tid & 7;
    const float* yr = yb + row * PY + j * 16;
    f32x4 v[4];
    float sum = 0.f, ss = 0.f;
    #pragma unroll
    for (int q = 0; q < 4; ++q) {
      v[q] = *(const f32x4*)(yr + q * 4);
      #pragma unroll
      for (int r = 0; r < 4; ++r) { sum += v[q][r]; ss += v[q][r] * v[q][r]; }
    }
    #pragma unroll
    for (int o = 1; o < 8; o <<= 1) {
      sum += __shfl_xor(sum, o, 64);
      ss  += __shfl_xor(ss, o, 64);
    }
    const float mu = sum * (1.0f / 128.0f);
    const float var = ss * (1.0f / 128.0f) - mu * mu;
    const float rstd = rsqrtf(var + 1e-5f);
    float* orow = out + (size_t)(e0 + row) * D_ + j * 16;
    #pragma unroll
    for (int q = 0; q < 4; ++q) {
      const f32x4 g = *(const f32x4*)(gamma + j * 16 + q * 4);
      const f32x4 bt = *(const f32x4*)(beta + j * 16 + q * 4);
      f32x4 o;
      #pragma unroll
      for (int r = 0; r < 4; ++r)
        o[r] = (v[q][r] - mu) * rstd * g[r] + bt[r];
      *(f32x4*)(orow + q * 4) = o;
    }
  }
}

// W [K][N] f32 -> Wt [N][K] bf16 (tiled transpose, coalesced both sides)
__global__ void prep_wt(const float* __restrict__ src, unsigned short* __restrict__ dst,
                        int K, int N) {
  __shared__ float tile[32][33];
  const int bk = blockIdx.x * 32, bn = blockIdx.y * 32;
  const int tx = threadIdx.x & 31, ty = threadIdx.x >> 5;
  #pragma unroll
  for (int i = ty; i < 32; i += 8)
    tile[i][tx] = src[(size_t)(bk + i) * N + bn + tx];
  __syncthreads();
  #pragma unroll
  for (int i = ty; i < 32; i += 8)
    dst[(size_t)(bn + i) * K + bk + tx] = f2bf(tile[tx][i]);
}

extern "C" void kernel_launch(void* const* d_in, const int* in_sizes, int n_in,
                              void* d_out, int out_size, void* d_ws, size_t ws_size,
                              hipStream_t stream) {
  const float* efeat    = (const float*)d_in[0];
  const float* src_feat = (const float*)d_in[1];
  const float* dst_feat = (const float*)d_in[2];
  const int*   src_idx  = (const int*)d_in[3];
  const int*   dst_idx  = (const int*)d_in[4];
  const float* W1 = (const float*)d_in[5];
  const float* b1 = (const float*)d_in[6];
  const float* W2 = (const float*)d_in[7];
  const float* b2 = (const float*)d_in[8];
  const float* W3 = (const float*)d_in[9];
  const float* b3 = (const float*)d_in[10];
  const float* gamma = (const float*)d_in[11];
  const float* beta  = (const float*)d_in[12];

  unsigned short* W1T = (unsigned short*)d_ws;          // [512][384]
  unsigned short* W2T = W1T + 512 * 384;                // [512][512]
  unsigned short* W3T = W2T + 512 * 512;                // [128][512]

  (void)hipFuncSetAttribute((const void*)edge_mlp_fused,
                            hipFuncAttributeMaxDynamicSharedMemorySize, LDS_BYTES);

  prep_wt<<<dim3(12, 16), 256, 0, stream>>>(W1, W1T, CAT_, H_);
  prep_wt<<<dim3(16, 16), 256, 0, stream>>>(W2, W2T, H_, H_);
  prep_wt<<<dim3(16, 4),  256, 0, stream>>>(W3, W3T, H_, D_);

  const int nblocks = 400000 / BM; // 6250, exact
  edge_mlp_fused<<<nblocks, 512, LDS_BYTES, stream>>>(
      efeat, src_feat, dst_feat, src_idx, dst_idx,
      W1T, W2T, W3T, b1, b2, b3, gamma, beta, (float*)d_out);
}

// Round 2
// 845.671 us; speedup vs baseline: 1.3531x; 1.3531x over previous
//
#include <hip/hip_runtime.h>
#include <hip/hip_bf16.h>
#include <cstdint>
#include <cstddef>

typedef __attribute__((ext_vector_type(4))) float f32x4;
typedef __attribute__((ext_vector_type(8))) short s16x8;

#define D_ 128
#define H_ 512
#define CAT_ 384
#define BM 128
#define NPAN 12        // 384 / 32
#define PPITCH 40      // panel pitch (bf16 elems): 32 + 8 pad -> 2-way banks, 16B aligned rows
#define PHP 520        // h pitch (bf16 elems): 512 + 8 pad
#define PYP 132        // y pitch (f32)
#define PAN_BYTES (BM * PPITCH * 2)            // 10240
#define H_BYTES (BM * PHP * 2)                 // 133120
#define LDS_BYTES (H_BYTES + 2 * PAN_BYTES)    // 153600 <= 160 KiB

__device__ __forceinline__ unsigned short f2bf(float x) {
  union { float f; unsigned u; } t; t.f = x;
  unsigned r = t.u + 0x7FFFu + ((t.u >> 16) & 1u);
  return (unsigned short)(r >> 16);
}

__global__ __launch_bounds__(512, 2)
void edge_mlp_fused(const float* __restrict__ efeat,
                    const float* __restrict__ src_feat,
                    const float* __restrict__ dst_feat,
                    const int* __restrict__ src_idx,
                    const int* __restrict__ dst_idx,
                    const unsigned short* __restrict__ W1T,
                    const unsigned short* __restrict__ W2T,
                    const unsigned short* __restrict__ W3T,
                    const float* __restrict__ b1,
                    const float* __restrict__ b2,
                    const float* __restrict__ b3,
                    const float* __restrict__ gamma,
                    const float* __restrict__ beta,
                    float* __restrict__ out) {
  extern __shared__ char smem[];
  unsigned short* hbuf = (unsigned short*)smem;                  // h1 -> h2 (barrier-separated reuse)
  unsigned short* pan[2];
  pan[0] = (unsigned short*)(smem + H_BYTES);
  pan[1] = pan[0] + BM * PPITCH;
  float* yb = (float*)smem;                                      // y overwrites h2 after GEMM3

  const int tid = threadIdx.x;
  const int lane = tid & 63;
  const int wave = tid >> 6;
  const size_t e0 = (size_t)blockIdx.x * BM;

  // ---- gather thread mapping: 4 threads per row, 8 f32 each per panel ----
  const int grow = tid >> 2;        // 0..127
  const int gq = tid & 2 ? (tid & 3) : (tid & 3); // = tid & 3
  const size_t e = e0 + grow;
  const float* gbase[3];
  gbase[0] = efeat + e * D_;
  gbase[1] = src_feat + (size_t)src_idx[e] * D_;
  gbase[2] = dst_feat + (size_t)dst_idx[e] * D_;

  const int arow = lane & 15;
  const int ak8 = (lane >> 4) * 8;
  const int c0 = lane & 15, r0 = (lane >> 4) * 4;

  f32x4 ga[2], gb[2];               // gather reg double-buffer

#define GLOAD(P, S) { const float* s_ = gbase[(P) >> 2] + ((P) & 3) * 32 + gq * 8; \
                      ga[S] = *(const f32x4*)s_; gb[S] = *(const f32x4*)(s_ + 4); }
#define PWRITE(P, S) { unsigned short* d_ = pan[(P) & 1] + grow * PPITCH + gq * 8; \
                       s16x8 w_; \
                       w_[0] = f2bf(ga[S][0]); w_[1] = f2bf(ga[S][1]); \
                       w_[2] = f2bf(ga[S][2]); w_[3] = f2bf(ga[S][3]); \
                       w_[4] = f2bf(gb[S][0]); w_[5] = f2bf(gb[S][1]); \
                       w_[6] = f2bf(gb[S][2]); w_[7] = f2bf(gb[S][3]); \
                       *(s16x8*)d_ = w_; }

  // ================= GEMM1: cat[128x384] @ W1 -> silu -> h1 =================
  {
    f32x4 acc[8][4];
    #pragma unroll
    for (int m = 0; m < 8; ++m)
      #pragma unroll
      for (int n = 0; n < 4; ++n) acc[m][n] = (f32x4){0.f, 0.f, 0.f, 0.f};

    const unsigned short* bp[4];
    #pragma unroll
    for (int n = 0; n < 4; ++n)
      bp[n] = W1T + (size_t)(wave * 64 + n * 16 + arow) * CAT_ + ak8;

    s16x8 bf[2][4];

    // prologue
    GLOAD(0, 0); PWRITE(0, 0); GLOAD(1, 1);
    #pragma unroll
    for (int n = 0; n < 4; ++n) bf[0][n] = *(const s16x8*)(bp[n]);
    __syncthreads();

    #pragma unroll
    for (int p = 0; p < NPAN; ++p) {
      if (p + 1 < NPAN) {
        PWRITE(p + 1, (p + 1) & 1);
        if (p + 2 < NPAN) GLOAD(p + 2, p & 1);
        #pragma unroll
        for (int n = 0; n < 4; ++n)
          bf[(p + 1) & 1][n] = *(const s16x8*)(bp[n] + (p + 1) * 32);
      }
      s16x8 a[8];
      const unsigned short* pb = pan[p & 1];
      #pragma unroll
      for (int m = 0; m < 8; ++m)
        a[m] = *(const s16x8*)(pb + (m * 16 + arow) * PPITCH + ak8);
      #pragma unroll
      for (int m = 0; m < 8; ++m)
        #pragma unroll
        for (int n = 0; n < 4; ++n)
          acc[m][n] = __builtin_amdgcn_mfma_f32_16x16x32_bf16(a[m], bf[p & 1][n], acc[m][n], 0, 0, 0);
      if (p + 1 < NPAN) __syncthreads();
    }

    // silu -> h1
    #pragma unroll
    for (int n = 0; n < 4; ++n) {
      const int col = wave * 64 + n * 16 + c0;
      const float bb = b1[col];
      #pragma unroll
      for (int m = 0; m < 8; ++m)
        #pragma unroll
        for (int r = 0; r < 4; ++r) {
          const float x = acc[m][n][r] + bb;
          hbuf[(m * 16 + r0 + r) * PHP + col] = f2bf(x / (1.0f + __expf(-x)));
        }
    }
  }
  __syncthreads();

  // ================= GEMM2: h1[128x512] @ W2 -> silu -> h2 (over h1) =================
  {
    f32x4 acc[8][4];
    #pragma unroll
    for (int m = 0; m < 8; ++m)
      #pragma unroll
      for (int n = 0; n < 4; ++n) acc[m][n] = (f32x4){0.f, 0.f, 0.f, 0.f};

    const unsigned short* bp[4];
    #pragma unroll
    for (int n = 0; n < 4; ++n)
      bp[n] = W2T + (size_t)(wave * 64 + n * 16 + arow) * H_ + ak8;

    s16x8 bf[2][4];
    #pragma unroll
    for (int n = 0; n < 4; ++n) bf[0][n] = *(const s16x8*)(bp[n]);

    #pragma unroll
    for (int kk = 0; kk < 16; ++kk) {
      if (kk + 1 < 16) {
        #pragma unroll
        for (int n = 0; n < 4; ++n)
          bf[(kk + 1) & 1][n] = *(const s16x8*)(bp[n] + (kk + 1) * 32);
      }
      s16x8 a[8];
      #pragma unroll
      for (int m = 0; m < 8; ++m)
        a[m] = *(const s16x8*)(hbuf + (m * 16 + arow) * PHP + kk * 32 + ak8);
      #pragma unroll
      for (int m = 0; m < 8; ++m)
        #pragma unroll
        for (int n = 0; n < 4; ++n)
          acc[m][n] = __builtin_amdgcn_mfma_f32_16x16x32_bf16(a[m], bf[kk & 1][n], acc[m][n], 0, 0, 0);
    }
    __syncthreads();   // everyone done READING h1 before overwriting with h2

    #pragma unroll
    for (int n = 0; n < 4; ++n) {
      const int col = wave * 64 + n * 16 + c0;
      const float bb = b2[col];
      #pragma unroll
      for (int m = 0; m < 8; ++m)
        #pragma unroll
        for (int r = 0; r < 4; ++r) {
          const float x = acc[m][n][r] + bb;
          hbuf[(m * 16 + r0 + r) * PHP + col] = f2bf(x / (1.0f + __expf(-x)));
        }
    }
  }
  __syncthreads();

  // ================= GEMM3: h2[128x512] @ W3 + b3 -> y (f32, over h2) =================
  {
    f32x4 acc[8];
    #pragma unroll
    for (int m = 0; m < 8; ++m) acc[m] = (f32x4){0.f, 0.f, 0.f, 0.f};

    const unsigned short* bp = W3T + (size_t)(wave * 16 + arow) * H_ + ak8;
    s16x8 bf[2];
    bf[0] = *(const s16x8*)(bp);

    #pragma unroll
    for (int kk = 0; kk < 16; ++kk) {
      if (kk + 1 < 16) bf[(kk + 1) & 1] = *(const s16x8*)(bp + (kk + 1) * 32);
      s16x8 a[8];
      #pragma unroll
      for (int m = 0; m < 8; ++m)
        a[m] = *(const s16x8*)(hbuf + (m * 16 + arow) * PHP + kk * 32 + ak8);
      #pragma unroll
      for (int m = 0; m < 8; ++m)
        acc[m] = __builtin_amdgcn_mfma_f32_16x16x32_bf16(a[m], bf[kk & 1], acc[m], 0, 0, 0);
    }
    __syncthreads();   // everyone done READING h2 before y overwrites the buffer

    const int col = wave * 16 + c0;
    const float bb = b3[col];
    #pragma unroll
    for (int m = 0; m < 8; ++m)
      #pragma unroll
      for (int r = 0; r < 4; ++r)
        yb[(m * 16 + r0 + r) * PYP + col] = acc[m][r] + bb;
  }
  __syncthreads();

  // ================= LayerNorm (f32) + store: 4 threads per row =================
  {
    const int row = tid >> 2, j = tid & 3;
    const float* yr = yb + row * PYP + j * 32;
    f32x4 v[8];
    float sum = 0.f, ss = 0.f;
    #pragma unroll
    for (int q = 0; q < 8; ++q) {
      v[q] = *(const f32x4*)(yr + q * 4);
      #pragma unroll
      for (int r = 0; r < 4; ++r) { sum += v[q][r]; ss += v[q][r] * v[q][r]; }
    }
    sum += __shfl_xor(sum, 1, 64); ss += __shfl_xor(ss, 1, 64);
    sum += __shfl_xor(sum, 2, 64); ss += __shfl_xor(ss, 2, 64);
    const float mu = sum * (1.0f / 128.0f);
    const float var = ss * (1.0f / 128.0f) - mu * mu;
    const float rstd = rsqrtf(var + 1e-5f);
    float* orow = out + (e0 + row) * D_ + j * 32;
    #pragma unroll
    for (int q = 0; q < 8; ++q) {
      const f32x4 g = *(const f32x4*)(gamma + j * 32 + q * 4);
      const f32x4 bt = *(const f32x4*)(beta + j * 32 + q * 4);
      f32x4 o;
      #pragma unroll
      for (int r = 0; r < 4; ++r)
        o[r] = (v[q][r] - mu) * rstd * g[r] + bt[r];
      *(f32x4*)(orow + q * 4) = o;
    }
  }
#undef GLOAD
#undef PWRITE
}

// W [K][N] f32 -> Wt [N][K] bf16 (tiled transpose, coalesced both sides)
__global__ void prep_wt(const float* __restrict__ src, unsigned short* __restrict__ dst,
                        int K, int N) {
  __shared__ float tile[32][33];
  const int bk = blockIdx.x * 32, bn = blockIdx.y * 32;
  const int tx = threadIdx.x & 31, ty = threadIdx.x >> 5;
  #pragma unroll
  for (int i = ty; i < 32; i += 8)
    tile[i][tx] = src[(size_t)(bk + i) * N + bn + tx];
  __syncthreads();
  #pragma unroll
  for (int i = ty; i < 32; i += 8)
    dst[(size_t)(bn + i) * K + bk + tx] = f2bf(tile[tx][i]);
}

extern "C" void kernel_launch(void* const* d_in, const int* in_sizes, int n_in,
                              void* d_out, int out_size, void* d_ws, size_t ws_size,
                              hipStream_t stream) {
  const float* efeat    = (const float*)d_in[0];
  const float* src_feat = (const float*)d_in[1];
  const float* dst_feat = (const float*)d_in[2];
  const int*   src_idx  = (const int*)d_in[3];
  const int*   dst_idx  = (const int*)d_in[4];
  const float* W1 = (const float*)d_in[5];
  const float* b1 = (const float*)d_in[6];
  const float* W2 = (const float*)d_in[7];
  const float* b2 = (const float*)d_in[8];
  const float* W3 = (const float*)d_in[9];
  const float* b3 = (const float*)d_in[10];
  const float* gamma = (const float*)d_in[11];
  const float* beta  = (const float*)d_in[12];

  unsigned short* W1T = (unsigned short*)d_ws;          // [512][384]
  unsigned short* W2T = W1T + 512 * 384;                // [512][512]
  unsigned short* W3T = W2T + 512 * 512;                // [128][512]

  (void)hipFuncSetAttribute((const void*)edge_mlp_fused,
                            hipFuncAttributeMaxDynamicSharedMemorySize, LDS_BYTES);

  prep_wt<<<dim3(12, 16), 256, 0, stream>>>(W1, W1T, CAT_, H_);
  prep_wt<<<dim3(16, 16), 256, 0, stream>>>(W2, W2T, H_, H_);
  prep_wt<<<dim3(16, 4),  256, 0, stream>>>(W3, W3T, H_, D_);

  const int nblocks = 400000 / BM; // 3125, exact
  edge_mlp_fused<<<nblocks, 512, LDS_BYTES, stream>>>(
      efeat, src_feat, dst_feat, src_idx, dst_idx,
      W1T, W2T, W3T, b1, b2, b3, gamma, beta, (float*)d_out);
}

// Round 3
// 828.195 us; speedup vs baseline: 1.3816x; 1.0211x over previous
//
#include <hip/hip_runtime.h>
#include <hip/hip_bf16.h>
#include <cstdint>
#include <cstddef>

typedef __attribute__((ext_vector_type(4))) float f32x4;
typedef __attribute__((ext_vector_type(8))) short s16x8;

#define D_ 128
#define H_ 512
#define CAT_ 384
#define BM 128
#define NPAN 12        // 384 / 32
#define PPITCH 40      // panel pitch (bf16): 32 + 8 pad
#define PHP 520        // h pitch (bf16): 512 + 8 pad
#define PYP 132        // y pitch (f32)
#define PAN_BYTES (BM * PPITCH * 2)            // 10240
#define H_BYTES (BM * PHP * 2)                 // 133120
#define LDS_BYTES (H_BYTES + 2 * PAN_BYTES)    // 153600 <= 160 KiB

__device__ __forceinline__ unsigned short f2bf(float x) {
  union { float f; unsigned u; } t; t.f = x;
  return (unsigned short)((t.u + 0x8000u) >> 16);  // round-half-up, 2 VALU ops
}

__global__ __launch_bounds__(1024, 4)
void edge_mlp_fused(const float* __restrict__ efeat,
                    const float* __restrict__ src_feat,
                    const float* __restrict__ dst_feat,
                    const int* __restrict__ src_idx,
                    const int* __restrict__ dst_idx,
                    const unsigned short* __restrict__ W1T,
                    const unsigned short* __restrict__ W2T,
                    const unsigned short* __restrict__ W3T,
                    const float* __restrict__ b1,
                    const float* __restrict__ b2,
                    const float* __restrict__ b3,
                    const float* __restrict__ gamma,
                    const float* __restrict__ beta,
                    float* __restrict__ out) {
  extern __shared__ char smem[];
  unsigned short* hbuf = (unsigned short*)smem;                  // h1 -> h2 (barrier-separated reuse)
  unsigned short* pan[2];
  pan[0] = (unsigned short*)(smem + H_BYTES);
  pan[1] = pan[0] + BM * PPITCH;
  float* yb = (float*)smem;                                      // y overwrites h after GEMM3

  const int tid = threadIdx.x;
  const int lane = tid & 63;
  const int wave = tid >> 6;          // 0..15
  const size_t e0 = (size_t)blockIdx.x * BM;

  // gather mapping: 8 threads per row, 1 f32x4 (4 floats) each per panel
  const int trow = tid >> 3;          // 0..127
  const int tq = tid & 7;             // 0..7
  const size_t e = e0 + trow;
  const float* gbase[3];
  gbase[0] = efeat + e * D_;
  gbase[1] = src_feat + (size_t)src_idx[e] * D_;
  gbase[2] = dst_feat + (size_t)dst_idx[e] * D_;

  const int arow = lane & 15;
  const int ak8 = (lane >> 4) * 8;
  const int c0 = lane & 15, r0 = (lane >> 4) * 4;

  f32x4 ga[2];                        // gather reg double-buffer

#define GLOAD(P, S) { ga[S] = *(const f32x4*)(gbase[(P) >> 2] + ((P) & 3) * 32 + tq * 4); }
#define PWRITE(P, S) { ushort4 w_; \
                       w_.x = f2bf(ga[S][0]); w_.y = f2bf(ga[S][1]); \
                       w_.z = f2bf(ga[S][2]); w_.w = f2bf(ga[S][3]); \
                       *(ushort4*)(pan[(P) & 1] + trow * PPITCH + tq * 4) = w_; }

  // ================= GEMM1: cat[128x384] @ W1 -> silu -> h1 =================
  {
    f32x4 acc[8][2];
    #pragma unroll
    for (int m = 0; m < 8; ++m)
      #pragma unroll
      for (int n = 0; n < 2; ++n) acc[m][n] = (f32x4){0.f, 0.f, 0.f, 0.f};

    const unsigned short* bp[2];
    #pragma unroll
    for (int n = 0; n < 2; ++n)
      bp[n] = W1T + (size_t)(wave * 32 + n * 16 + arow) * CAT_ + ak8;

    s16x8 bf[2][2];

    GLOAD(0, 0); PWRITE(0, 0); GLOAD(1, 1);
    #pragma unroll
    for (int n = 0; n < 2; ++n) bf[0][n] = *(const s16x8*)(bp[n]);
    __syncthreads();

    #pragma unroll
    for (int p = 0; p < NPAN; ++p) {
      if (p + 1 < NPAN) {
        PWRITE(p + 1, (p + 1) & 1);
        if (p + 2 < NPAN) GLOAD(p + 2, p & 1);
        #pragma unroll
        for (int n = 0; n < 2; ++n)
          bf[(p + 1) & 1][n] = *(const s16x8*)(bp[n] + (p + 1) * 32);
      }
      const unsigned short* pb = pan[p & 1];
      #pragma unroll
      for (int mh = 0; mh < 2; ++mh) {     // chunk A loads: 4 frags at a time
        s16x8 a[4];
        #pragma unroll
        for (int m = 0; m < 4; ++m)
          a[m] = *(const s16x8*)(pb + ((mh * 4 + m) * 16 + arow) * PPITCH + ak8);
        #pragma unroll
        for (int m = 0; m < 4; ++m)
          #pragma unroll
          for (int n = 0; n < 2; ++n)
            acc[mh * 4 + m][n] = __builtin_amdgcn_mfma_f32_16x16x32_bf16(a[m], bf[p & 1][n], acc[mh * 4 + m][n], 0, 0, 0);
      }
      if (p + 1 < NPAN) __syncthreads();
    }

    #pragma unroll
    for (int n = 0; n < 2; ++n) {
      const int col = wave * 32 + n * 16 + c0;
      const float bb = b1[col];
      #pragma unroll
      for (int m = 0; m < 8; ++m)
        #pragma unroll
        for (int r = 0; r < 4; ++r) {
          const float x = acc[m][n][r] + bb;
          hbuf[(m * 16 + r0 + r) * PHP + col] = f2bf(x / (1.0f + __expf(-x)));
        }
    }
  }
  __syncthreads();

  // ================= GEMM2: h1[128x512] @ W2 -> silu -> h2 (over h1) =================
  {
    f32x4 acc[8][2];
    #pragma unroll
    for (int m = 0; m < 8; ++m)
      #pragma unroll
      for (int n = 0; n < 2; ++n) acc[m][n] = (f32x4){0.f, 0.f, 0.f, 0.f};

    const unsigned short* bp[2];
    #pragma unroll
    for (int n = 0; n < 2; ++n)
      bp[n] = W2T + (size_t)(wave * 32 + n * 16 + arow) * H_ + ak8;

    s16x8 bf[2][2];
    #pragma unroll
    for (int n = 0; n < 2; ++n) bf[0][n] = *(const s16x8*)(bp[n]);

    #pragma unroll
    for (int kk = 0; kk < 16; ++kk) {
      if (kk + 1 < 16) {
        #pragma unroll
        for (int n = 0; n < 2; ++n)
          bf[(kk + 1) & 1][n] = *(const s16x8*)(bp[n] + (kk + 1) * 32);
      }
      #pragma unroll
      for (int mh = 0; mh < 2; ++mh) {
        s16x8 a[4];
        #pragma unroll
        for (int m = 0; m < 4; ++m)
          a[m] = *(const s16x8*)(hbuf + ((mh * 4 + m) * 16 + arow) * PHP + kk * 32 + ak8);
        #pragma unroll
        for (int m = 0; m < 4; ++m)
          #pragma unroll
          for (int n = 0; n < 2; ++n)
            acc[mh * 4 + m][n] = __builtin_amdgcn_mfma_f32_16x16x32_bf16(a[m], bf[kk & 1][n], acc[mh * 4 + m][n], 0, 0, 0);
      }
    }
    __syncthreads();   // all waves done READING h1 before overwrite

    #pragma unroll
    for (int n = 0; n < 2; ++n) {
      const int col = wave * 32 + n * 16 + c0;
      const float bb = b2[col];
      #pragma unroll
      for (int m = 0; m < 8; ++m)
        #pragma unroll
        for (int r = 0; r < 4; ++r) {
          const float x = acc[m][n][r] + bb;
          hbuf[(m * 16 + r0 + r) * PHP + col] = f2bf(x / (1.0f + __expf(-x)));
        }
    }
  }
  __syncthreads();

  // ========== GEMM3: h2[128x512] @ W3 + b3 -> y (f32, over h2); 2M x 8N wave split ==========
  {
    const int ms = wave >> 3;          // 0..1 : M half
    const int nq = wave & 7;           // 0..7 : N 16-col slice
    f32x4 acc[4];
    #pragma unroll
    for (int m = 0; m < 4; ++m) acc[m] = (f32x4){0.f, 0.f, 0.f, 0.f};

    const unsigned short* bp = W3T + (size_t)(nq * 16 + arow) * H_ + ak8;
    s16x8 bf[2];
    bf[0] = *(const s16x8*)(bp);

    #pragma unroll
    for (int kk = 0; kk < 16; ++kk) {
      if (kk + 1 < 16) bf[(kk + 1) & 1] = *(const s16x8*)(bp + (kk + 1) * 32);
      s16x8 a[4];
      #pragma unroll
      for (int m = 0; m < 4; ++m)
        a[m] = *(const s16x8*)(hbuf + ((ms * 64 + m * 16 + arow)) * PHP + kk * 32 + ak8);
      #pragma unroll
      for (int m = 0; m < 4; ++m)
        acc[m] = __builtin_amdgcn_mfma_f32_16x16x32_bf16(a[m], bf[kk & 1], acc[m], 0, 0, 0);
    }
    __syncthreads();   // all waves done READING h2 before y overwrites buffer

    const int col = nq * 16 + c0;
    const float bb = b3[col];
    #pragma unroll
    for (int m = 0; m < 4; ++m)
      #pragma unroll
      for (int r = 0; r < 4; ++r)
        yb[(ms * 64 + m * 16 + r0 + r) * PYP + col] = acc[m][r] + bb;
  }
  __syncthreads();

  // ================= LayerNorm (f32) + store: 8 threads per row =================
  {
    const int row = tid >> 3, j = tid & 7;
    const float* yr = yb + row * PYP + j * 16;
    f32x4 v[4];
    float sum = 0.f, ss = 0.f;
    #pragma unroll
    for (int q = 0; q < 4; ++q) {
      v[q] = *(const f32x4*)(yr + q * 4);
      #pragma unroll
      for (int r = 0; r < 4; ++r) { sum += v[q][r]; ss += v[q][r] * v[q][r]; }
    }
    sum += __shfl_xor(sum, 1, 64); ss += __shfl_xor(ss, 1, 64);
    sum += __shfl_xor(sum, 2, 64); ss += __shfl_xor(ss, 2, 64);
    sum += __shfl_xor(sum, 4, 64); ss += __shfl_xor(ss, 4, 64);
    const float mu = sum * (1.0f / 128.0f);
    const float var = ss * (1.0f / 128.0f) - mu * mu;
    const float rstd = rsqrtf(var + 1e-5f);
    float* orow = out + (e0 + row) * D_ + j * 16;
    #pragma unroll
    for (int q = 0; q < 4; ++q) {
      const f32x4 g = *(const f32x4*)(gamma + j * 16 + q * 4);
      const f32x4 bt = *(const f32x4*)(beta + j * 16 + q * 4);
      f32x4 o;
      #pragma unroll
      for (int r = 0; r < 4; ++r)
        o[r] = (v[q][r] - mu) * rstd * g[r] + bt[r];
      *(f32x4*)(orow + q * 4) = o;
    }
  }
#undef GLOAD
#undef PWRITE
}

// W [K][N] f32 -> Wt [N][K] bf16 (tiled transpose, coalesced both sides)
__global__ void prep_wt(const float* __restrict__ src, unsigned short* __restrict__ dst,
                        int K, int N) {
  __shared__ float tile[32][33];
  const int bk = blockIdx.x * 32, bn = blockIdx.y * 32;
  const int tx = threadIdx.x & 31, ty = threadIdx.x >> 5;
  #pragma unroll
  for (int i = ty; i < 32; i += 8)
    tile[i][tx] = src[(size_t)(bk + i) * N + bn + tx];
  __syncthreads();
  #pragma unroll
  for (int i = ty; i < 32; i += 8)
    dst[(size_t)(bn + i) * K + bk + tx] = f2bf(tile[tx][i]);
}

extern "C" void kernel_launch(void* const* d_in, const int* in_sizes, int n_in,
                              void* d_out, int out_size, void* d_ws, size_t ws_size,
                              hipStream_t stream) {
  const float* efeat    = (const float*)d_in[0];
  const float* src_feat = (const float*)d_in[1];
  const float* dst_feat = (const float*)d_in[2];
  const int*   src_idx  = (const int*)d_in[3];
  const int*   dst_idx  = (const int*)d_in[4];
  const float* W1 = (const float*)d_in[5];
  const float* b1 = (const float*)d_in[6];
  const float* W2 = (const float*)d_in[7];
  const float* b2 = (const float*)d_in[8];
  const float* W3 = (const float*)d_in[9];
  const float* b3 = (const float*)d_in[10];
  const float* gamma = (const float*)d_in[11];
  const float* beta  = (const float*)d_in[12];

  unsigned short* W1T = (unsigned short*)d_ws;          // [512][384]
  unsigned short* W2T = W1T + 512 * 384;                // [512][512]
  unsigned short* W3T = W2T + 512 * 512;                // [128][512]

  (void)hipFuncSetAttribute((const void*)edge_mlp_fused,
                            hipFuncAttributeMaxDynamicSharedMemorySize, LDS_BYTES);

  prep_wt<<<dim3(12, 16), 256, 0, stream>>>(W1, W1T, CAT_, H_);
  prep_wt<<<dim3(16, 16), 256, 0, stream>>>(W2, W2T, H_, H_);
  prep_wt<<<dim3(16, 4),  256, 0, stream>>>(W3, W3T, H_, D_);

  const int nblocks = 400000 / BM; // 3125, exact
  edge_mlp_fused<<<nblocks, 1024, LDS_BYTES, stream>>>(
      efeat, src_feat, dst_feat, src_idx, dst_idx,
      W1T, W2T, W3T, b1, b2, b3, gamma, beta, (float*)d_out);
}